// Round 7
// baseline (512.584 us; speedup 1.0000x reference)
//
#include <hip/hip_runtime.h>

// ---------------- types ----------------
typedef __bf16 bf16x8 __attribute__((ext_vector_type(8)));
typedef __bf16 bf16x4 __attribute__((ext_vector_type(4)));
typedef float  f32x4  __attribute__((ext_vector_type(4)));
typedef short  s16x4  __attribute__((ext_vector_type(4)));

#define AS1 __attribute__((address_space(1)))
#define AS3 __attribute__((address_space(3)))

__device__ inline void gload_lds16(const void* g, void* l) {
  __builtin_amdgcn_global_load_lds((AS1 void*)(g), (AS3 void*)(l), 16, 0, 0);
}

#if __has_builtin(__builtin_amdgcn_exp2f)
#define EXP2(x) __builtin_amdgcn_exp2f(x)
#else
#define EXP2(x) exp2f(x)
#endif

#if __has_builtin(__builtin_amdgcn_mfma_f32_16x16x16bf16_1k)
#define PV_K16 1
#define MFMA16(a, b, c) __builtin_amdgcn_mfma_f32_16x16x16bf16_1k(a, b, c, 0, 0, 0)
#else
#define PV_K16 0
#endif

__device__ inline short bf2s(__bf16 x) {
  union { __bf16 b; short s; } u; u.b = x; return u.s;
}

// ---------------- constants ----------------
#define CB 2
#define CS 2048
#define CE 1024
#define CH 16
#define CD 64
#define GM 4096
#define GN 1024
#define GK 1024

// Q pre-scale: (1/sqrt(H)) * log2(e) so attn uses exp2 directly.
#define QSCALE 0.36067376022224087f

// workspace element offsets (__bf16 units)
#define WS_WQ  0
#define WS_WK  1048576
#define WS_WV  2097152
#define WS_WO  3145728
#define WS_XQ  4194304
#define WS_XK  8388608
#define WS_XV  12582912
#define WS_QH  16777216
#define WS_KH  20971520
#define WS_VT  25165824
#define WS_AO  WS_XQ   // Xq dead when attention writes AO

// ---------------- fp32 -> bf16 conversion (8 elems/thread, 16B stores) ----
__global__ __launch_bounds__(256) void convert_all(
    const float* __restrict__ q, const float* __restrict__ k, const float* __restrict__ v,
    const float* __restrict__ wq, const float* __restrict__ wk,
    const float* __restrict__ wv, const float* __restrict__ wo,
    __bf16* __restrict__ ws) {
  long idx = ((long)blockIdx.x * 256 + threadIdx.x) * 8;
  const float* src;
  __bf16* dst;
  if (idx < 12582912) {
    int a = (int)(idx >> 22);
    long within = idx & 4194303;
    src = (a == 0 ? q : (a == 1 ? k : v)) + within;
    dst = ws + WS_XQ + (long)a * 4194304 + within;
  } else {
    long widx = idx - 12582912;
    int a = (int)(widx >> 20);
    long within = widx & 1048575;
    src = (a == 0 ? wq : (a == 1 ? wk : (a == 2 ? wv : wo))) + within;
    dst = ws + widx;
  }
  float4 f0 = *(const float4*)src;
  float4 f1 = *(const float4*)(src + 4);
  bf16x8 o;
  o[0] = (__bf16)f0.x; o[1] = (__bf16)f0.y; o[2] = (__bf16)f0.z; o[3] = (__bf16)f0.w;
  o[4] = (__bf16)f1.x; o[5] = (__bf16)f1.y; o[6] = (__bf16)f1.z; o[7] = (__bf16)f1.w;
  *(bf16x8*)dst = o;
}

// ======== BK=64 GEMM core with XOR-swizzled LDS (R4, conflict-free) ========
#define GEMM_BK64_BODY(A_PTR, B_PTR, KLEN)                                          \
  __shared__ __bf16 As[8192];                                                       \
  __shared__ __bf16 Bs[8192];                                                       \
  const int tid = threadIdx.x;                                                      \
  const int w = tid >> 6, l = tid & 63;                                             \
  const int wm = w >> 1, wn = w & 1;                                                \
  const int bm = blockIdx.y * 128, bn = blockIdx.x * 128;                           \
  const int lr = l & 15, lq = l >> 4;                                               \
  f32x4 acc[4][4] = {};                                                             \
  const int srow = w * 8 + (l >> 3);                                                \
  const int scol = ((l & 7) ^ ((l >> 3) & 7)) * 8;                                  \
  const __bf16* ga0 = (A_PTR) + (size_t)(bm + srow) * GK + scol;                    \
  const __bf16* gb0 = (B_PTR) + (size_t)(bn + srow) * GK + scol;                    \
  const int dstg = w * 64 + l;                                                      \
  for (int k0 = 0; k0 < (KLEN); k0 += 64) {                                         \
    __syncthreads();                                                                \
    for (int i = 0; i < 4; i++) {                                                   \
      gload_lds16(ga0 + (size_t)(i * 32) * GK + k0, &As[(i * 256 + dstg) * 8]);     \
      gload_lds16(gb0 + (size_t)(i * 32) * GK + k0, &Bs[(i * 256 + dstg) * 8]);     \
    }                                                                               \
    __syncthreads();                                                                \
    for (int kk = 0; kk < 2; kk++) {                                                \
      bf16x8 af[4], bfr[4];                                                         \
      for (int mi = 0; mi < 4; mi++) {                                              \
        const int row = wm * 64 + mi * 16 + lr;                                     \
        af[mi] = *(const bf16x8*)&As[(row * 8 + ((kk * 4 + lq) ^ (row & 7))) * 8];  \
      }                                                                             \
      for (int ni = 0; ni < 4; ni++) {                                              \
        const int row = wn * 64 + ni * 16 + lr;                                     \
        bfr[ni] = *(const bf16x8*)&Bs[(row * 8 + ((kk * 4 + lq) ^ (row & 7))) * 8]; \
      }                                                                             \
      for (int mi = 0; mi < 4; mi++)                                                \
        for (int ni = 0; ni < 4; ni++)                                              \
          acc[mi][ni] = __builtin_amdgcn_mfma_f32_16x16x32_bf16(af[mi], bfr[ni],    \
                                                                acc[mi][ni], 0, 0, 0); \
    }                                                                               \
  }

// ---------------- fused QKV GEMM: grid (8, 32, 3) ----------------
__global__ __launch_bounds__(256) void qkv_gemm(
    const __bf16* __restrict__ Xq, const __bf16* __restrict__ Xk, const __bf16* __restrict__ Xv,
    const __bf16* __restrict__ Wq, const __bf16* __restrict__ Wk, const __bf16* __restrict__ Wv,
    const float* __restrict__ bq, const float* __restrict__ bk, const float* __restrict__ bv,
    __bf16* __restrict__ Qh, __bf16* __restrict__ Kh, __bf16* __restrict__ Vt) {
  const int mode = blockIdx.z;
  const __bf16* A  = mode == 0 ? Xq : (mode == 1 ? Xk : Xv);
  const __bf16* Bw = mode == 0 ? Wq : (mode == 1 ? Wk : Wv);
  const float* bias = mode == 0 ? bq : (mode == 1 ? bk : bv);

  GEMM_BK64_BODY(A, Bw, GK)

  const int row0 = bm + wm * 64;
  const int col0 = bn + wn * 64;
  for (int ni = 0; ni < 4; ni++) {
    const int col = col0 + ni * 16 + lr;
    const float bb = bias[col];
    for (int mi = 0; mi < 4; mi++) {
      const int row = row0 + mi * 16 + lq * 4;
      if (mode == 0) {
        for (int r = 0; r < 4; r++)
          Qh[(size_t)(row + r) * GN + col] = (__bf16)((acc[mi][ni][r] + bb) * QSCALE);
      } else if (mode == 1) {
        for (int r = 0; r < 4; r++)
          Kh[(size_t)(row + r) * GN + col] = (__bf16)(acc[mi][ni][r] + bb);
      } else {
        const int b = row >> 11, s = row & 2047;
        const int h = col >> 6, d = col & 63;
        bf16x4 pk;
        for (int r = 0; r < 4; r++) pk[r] = (__bf16)(acc[mi][ni][r] + bb);
        *(bf16x4*)&Vt[(size_t)((b * CH + h) * CD + d) * CS + s] = pk;
      }
    }
  }
}

// ---------------- Wo GEMM: grid (8, 32), direct store (no atomics) --------
__global__ __launch_bounds__(256) void gemm_wo(const __bf16* __restrict__ Ain,
                                               const __bf16* __restrict__ Bw,
                                               const float* __restrict__ bias,
                                               float* __restrict__ O) {
  GEMM_BK64_BODY(Ain, Bw, GK)

  const int row0 = bm + wm * 64;
  const int col0 = bn + wn * 64;
  for (int ni = 0; ni < 4; ni++) {
    const int col = col0 + ni * 16 + lr;
    const float bb = bias[col];
    for (int mi = 0; mi < 4; mi++) {
      const int row = row0 + mi * 16 + lq * 4;
      for (int r = 0; r < 4; r++)
        O[(size_t)(row + r) * GN + col] = acc[mi][ni][r] + bb;
    }
  }
}

// ---------------- fused flash attention v7: LDS-free, barrier-free --------
// 512 threads = 8 waves x 16 q-rows (128 q/block). S^T = K.Q^T (R3-verified
// coords), fast exp2 (R5), K=16 PV (R5). K-frags (16B) and V-frags (8B) are
// read DIRECTLY from global: Kh rows give the S^T A-operand, Vt [b,h,d,s]
// gives the PV B-operand. No staging, no __syncthreads, no vmcnt(0) drain;
// waves free-run, L1 dedups the w-independent frag reads, same-bh blocks
// share an XCD's L2 (blockIdx.x % 8).
__global__ __launch_bounds__(512, 4) void attn(const __bf16* __restrict__ Qh,
                                               const __bf16* __restrict__ Kh,
                                               const __bf16* __restrict__ Vt,
                                               __bf16* __restrict__ AO) {
  const int tid = threadIdx.x, w = tid >> 6, l = tid & 63;
  const int lr = l & 15, lq = l >> 4;
  const int bh = blockIdx.x;
  const int b = bh >> 4, h = bh & 15;
  const int q0 = blockIdx.y * 128 + w * 16;

  // Q as B-operand: B[n=q=lr][k=d=kk*32+lq*8+j]  (Qh pre-scaled by QSCALE)
  bf16x8 qf[2];
  for (int kk = 0; kk < 2; kk++)
    qf[kk] = *(const bf16x8*)&Qh[((size_t)b * CS + q0 + lr) * CE + h * CD + kk * 32 + lq * 8];

  const __bf16* Kbase = Kh + (size_t)b * CS * CE + h * CD;
  const __bf16* Vbase = Vt + (size_t)bh * CD * CS;

  f32x4 o[4] = {};
  float lsum = 0.f;
#if !PV_K16
  const bool hi_half = (lq & 1);
#endif

  for (int kt = 0; kt < CS / 128; kt++) {
    const int key0 = kt * 128;

    // S^T = K.Q^T : sa[ni][r] <-> key = key0+ni*16+lq*4+r, q = q0+lr
    f32x4 sa[8] = {};
    for (int kk = 0; kk < 2; kk++) {
      bf16x8 kf[8];
      for (int ni = 0; ni < 8; ni++)
        kf[ni] = *(const bf16x8*)&Kbase[(size_t)(key0 + ni * 16 + lr) * CE + kk * 32 + lq * 8];
      for (int ni = 0; ni < 8; ni++)
        sa[ni] = __builtin_amdgcn_mfma_f32_16x16x32_bf16(kf[ni], qf[kk], sa[ni], 0, 0, 0);
    }

#if PV_K16
    // exp2 -> direct K=16 A-frag; V B-frag = 8B contiguous s-run of Vt
    for (int ni = 0; ni < 8; ni++) {
      s16x4 pa4;
      for (int r = 0; r < 4; r++) {
        const float p = EXP2(sa[ni][r]);
        lsum += p;
        pa4[r] = bf2s((__bf16)p);
      }
      const int kb = key0 + ni * 16 + lq * 4;
      for (int di = 0; di < 4; di++) {
        const s16x4 vb4 = *(const s16x4*)&Vbase[(size_t)(di * 16 + lr) * CS + kb];
        o[di] = MFMA16(pa4, vb4, o[di]);
      }
    }
#else
    // fallback: zero-padded K=32 PV, V frag 16B from global
    for (int ni = 0; ni < 8; ni++) {
      bf16x8 pa;
      for (int r = 0; r < 4; r++) {
        const float p = EXP2(sa[ni][r]);
        lsum += p;
        const __bf16 bv = (__bf16)p;
        pa[r]     = hi_half ? (__bf16)0.f : bv;
        pa[4 + r] = hi_half ? bv : (__bf16)0.f;
      }
      const int kb = key0 + ni * 16 + (lq >> 1) * 8;
      for (int di = 0; di < 4; di++) {
        const bf16x8 vb = *(const bf16x8*)&Vbase[(size_t)(di * 16 + lr) * CS + kb];
        o[di] = __builtin_amdgcn_mfma_f32_16x16x32_bf16(pa, vb, o[di], 0, 0, 0);
      }
    }
#endif
  }

  // deferred row-sum: lane partial for q = q0+lr over keys {16ni + lq*4+r}
  lsum += __shfl_xor(lsum, 16, 64);
  lsum += __shfl_xor(lsum, 32, 64);

  // o C-layout: row q_local = lq*4+r, col d = di*16+lr
  f32x4 rv;
  for (int r = 0; r < 4; r++) rv[r] = 1.0f / __shfl(lsum, lq * 4 + r, 64);
  for (int di = 0; di < 4; di++)
    for (int r = 0; r < 4; r++) {
      const size_t s = q0 + lq * 4 + r;
      AO[((size_t)b * CS + s) * CE + h * CD + di * 16 + lr] = (__bf16)(o[di][r] * rv[r]);
    }
}

// ---------------- launch ----------------
extern "C" void kernel_launch(void* const* d_in, const int* in_sizes, int n_in,
                              void* d_out, int out_size, void* d_ws, size_t ws_size,
                              hipStream_t stream) {
  (void)in_sizes; (void)n_in; (void)out_size; (void)ws_size;
  const float* q  = (const float*)d_in[0];
  const float* k  = (const float*)d_in[1];
  const float* v  = (const float*)d_in[2];
  const float* Wq = (const float*)d_in[3];
  const float* bq = (const float*)d_in[4];
  const float* Wk = (const float*)d_in[5];
  const float* bk = (const float*)d_in[6];
  const float* Wv = (const float*)d_in[7];
  const float* bv = (const float*)d_in[8];
  const float* Wo = (const float*)d_in[9];
  const float* bo = (const float*)d_in[10];

  __bf16* ws = (__bf16*)d_ws;
  __bf16 *Wq_b = ws + WS_WQ, *Wk_b = ws + WS_WK, *Wv_b = ws + WS_WV, *Wo_b = ws + WS_WO;
  __bf16 *Xq = ws + WS_XQ, *Xk = ws + WS_XK, *Xv = ws + WS_XV;
  __bf16 *Qh = ws + WS_QH, *Kh = ws + WS_KH, *Vt = ws + WS_VT;
  __bf16 *AO = ws + WS_AO;

  convert_all<<<8192, 256, 0, stream>>>(q, k, v, Wq, Wk, Wv, Wo, ws);

  qkv_gemm<<<dim3(GN / 128, GM / 128, 3), 256, 0, stream>>>(
      Xq, Xk, Xv, Wq_b, Wk_b, Wv_b, bq, bk, bv, Qh, Kh, Vt);

  attn<<<dim3(CB * CH, CS / 128), 512, 0, stream>>>(Qh, Kh, Vt, AO);

  gemm_wo<<<dim3(GN / 128, GM / 128), 256, 0, stream>>>(AO, Wo_b, bo, (float*)d_out);
}

// Round 8
// 329.495 us; speedup vs baseline: 1.5557x; 1.5557x over previous
//
#include <hip/hip_runtime.h>

// ---------------- types ----------------
typedef __bf16 bf16x8 __attribute__((ext_vector_type(8)));
typedef __bf16 bf16x4 __attribute__((ext_vector_type(4)));
typedef float  f32x4  __attribute__((ext_vector_type(4)));
typedef short  s16x4  __attribute__((ext_vector_type(4)));

#define AS1 __attribute__((address_space(1)))
#define AS3 __attribute__((address_space(3)))

__device__ inline void gload_lds16(const void* g, void* l) {
  __builtin_amdgcn_global_load_lds((AS1 void*)(g), (AS3 void*)(l), 16, 0, 0);
}

#if __has_builtin(__builtin_amdgcn_exp2f)
#define EXP2(x) __builtin_amdgcn_exp2f(x)
#else
#define EXP2(x) exp2f(x)
#endif

#if __has_builtin(__builtin_amdgcn_mfma_f32_16x16x16bf16_1k)
#define PV_K16 1
#define MFMA16(a, b, c) __builtin_amdgcn_mfma_f32_16x16x16bf16_1k(a, b, c, 0, 0, 0)
#else
#define PV_K16 0
#endif

__device__ inline short bf2s(__bf16 x) {
  union { __bf16 b; short s; } u; u.b = x; return u.s;
}

// ---------------- constants ----------------
#define CB 2
#define CS 2048
#define CE 1024
#define CH 16
#define CD 64
#define GM 4096
#define GN 1024
#define GK 1024

// Q pre-scale: (1/sqrt(H)) * log2(e) so attn uses exp2 directly.
#define QSCALE 0.36067376022224087f

// workspace element offsets (__bf16 units)
#define WS_WQ  0
#define WS_WK  1048576
#define WS_WV  2097152
#define WS_WO  3145728
#define WS_XQ  4194304
#define WS_XK  8388608
#define WS_XV  12582912
#define WS_QH  16777216
#define WS_KH  20971520
#define WS_VT  25165824
#define WS_AO  WS_XQ   // Xq dead when attention writes AO

// ---------------- fp32 -> bf16 conversion (8 elems/thread, 16B stores) ----
__global__ __launch_bounds__(256) void convert_all(
    const float* __restrict__ q, const float* __restrict__ k, const float* __restrict__ v,
    const float* __restrict__ wq, const float* __restrict__ wk,
    const float* __restrict__ wv, const float* __restrict__ wo,
    __bf16* __restrict__ ws) {
  long idx = ((long)blockIdx.x * 256 + threadIdx.x) * 8;
  const float* src;
  __bf16* dst;
  if (idx < 12582912) {
    int a = (int)(idx >> 22);
    long within = idx & 4194303;
    src = (a == 0 ? q : (a == 1 ? k : v)) + within;
    dst = ws + WS_XQ + (long)a * 4194304 + within;
  } else {
    long widx = idx - 12582912;
    int a = (int)(widx >> 20);
    long within = widx & 1048575;
    src = (a == 0 ? wq : (a == 1 ? wk : (a == 2 ? wv : wo))) + within;
    dst = ws + widx;
  }
  float4 f0 = *(const float4*)src;
  float4 f1 = *(const float4*)(src + 4);
  bf16x8 o;
  o[0] = (__bf16)f0.x; o[1] = (__bf16)f0.y; o[2] = (__bf16)f0.z; o[3] = (__bf16)f0.w;
  o[4] = (__bf16)f1.x; o[5] = (__bf16)f1.y; o[6] = (__bf16)f1.z; o[7] = (__bf16)f1.w;
  *(bf16x8*)dst = o;
}

// ======== BK=64 GEMM core with XOR-swizzled LDS (R4, conflict-free) ========
#define GEMM_BK64_BODY(A_PTR, B_PTR, KLEN)                                          \
  __shared__ __bf16 As[8192];                                                       \
  __shared__ __bf16 Bs[8192];                                                       \
  const int tid = threadIdx.x;                                                      \
  const int w = tid >> 6, l = tid & 63;                                             \
  const int wm = w >> 1, wn = w & 1;                                                \
  const int bm = blockIdx.y * 128, bn = blockIdx.x * 128;                           \
  const int lr = l & 15, lq = l >> 4;                                               \
  f32x4 acc[4][4] = {};                                                             \
  const int srow = w * 8 + (l >> 3);                                                \
  const int scol = ((l & 7) ^ ((l >> 3) & 7)) * 8;                                  \
  const __bf16* ga0 = (A_PTR) + (size_t)(bm + srow) * GK + scol;                    \
  const __bf16* gb0 = (B_PTR) + (size_t)(bn + srow) * GK + scol;                    \
  const int dstg = w * 64 + l;                                                      \
  for (int k0 = 0; k0 < (KLEN); k0 += 64) {                                         \
    __syncthreads();                                                                \
    for (int i = 0; i < 4; i++) {                                                   \
      gload_lds16(ga0 + (size_t)(i * 32) * GK + k0, &As[(i * 256 + dstg) * 8]);     \
      gload_lds16(gb0 + (size_t)(i * 32) * GK + k0, &Bs[(i * 256 + dstg) * 8]);     \
    }                                                                               \
    __syncthreads();                                                                \
    for (int kk = 0; kk < 2; kk++) {                                                \
      bf16x8 af[4], bfr[4];                                                         \
      for (int mi = 0; mi < 4; mi++) {                                              \
        const int row = wm * 64 + mi * 16 + lr;                                     \
        af[mi] = *(const bf16x8*)&As[(row * 8 + ((kk * 4 + lq) ^ (row & 7))) * 8];  \
      }                                                                             \
      for (int ni = 0; ni < 4; ni++) {                                              \
        const int row = wn * 64 + ni * 16 + lr;                                     \
        bfr[ni] = *(const bf16x8*)&Bs[(row * 8 + ((kk * 4 + lq) ^ (row & 7))) * 8]; \
      }                                                                             \
      for (int mi = 0; mi < 4; mi++)                                                \
        for (int ni = 0; ni < 4; ni++)                                              \
          acc[mi][ni] = __builtin_amdgcn_mfma_f32_16x16x32_bf16(af[mi], bfr[ni],    \
                                                                acc[mi][ni], 0, 0, 0); \
    }                                                                               \
  }

// ---------------- fused QKV GEMM: grid (8, 32, 3) ----------------
__global__ __launch_bounds__(256) void qkv_gemm(
    const __bf16* __restrict__ Xq, const __bf16* __restrict__ Xk, const __bf16* __restrict__ Xv,
    const __bf16* __restrict__ Wq, const __bf16* __restrict__ Wk, const __bf16* __restrict__ Wv,
    const float* __restrict__ bq, const float* __restrict__ bk, const float* __restrict__ bv,
    __bf16* __restrict__ Qh, __bf16* __restrict__ Kh, __bf16* __restrict__ Vt) {
  const int mode = blockIdx.z;
  const __bf16* A  = mode == 0 ? Xq : (mode == 1 ? Xk : Xv);
  const __bf16* Bw = mode == 0 ? Wq : (mode == 1 ? Wk : Wv);
  const float* bias = mode == 0 ? bq : (mode == 1 ? bk : bv);

  GEMM_BK64_BODY(A, Bw, GK)

  const int row0 = bm + wm * 64;
  const int col0 = bn + wn * 64;
  for (int ni = 0; ni < 4; ni++) {
    const int col = col0 + ni * 16 + lr;
    const float bb = bias[col];
    for (int mi = 0; mi < 4; mi++) {
      const int row = row0 + mi * 16 + lq * 4;
      if (mode == 0) {
        for (int r = 0; r < 4; r++)
          Qh[(size_t)(row + r) * GN + col] = (__bf16)((acc[mi][ni][r] + bb) * QSCALE);
      } else if (mode == 1) {
        for (int r = 0; r < 4; r++)
          Kh[(size_t)(row + r) * GN + col] = (__bf16)(acc[mi][ni][r] + bb);
      } else {
        const int b = row >> 11, s = row & 2047;
        const int h = col >> 6, d = col & 63;
        bf16x4 pk;
        for (int r = 0; r < 4; r++) pk[r] = (__bf16)(acc[mi][ni][r] + bb);
        *(bf16x4*)&Vt[(size_t)((b * CH + h) * CD + d) * CS + s] = pk;
      }
    }
  }
}

// ---------------- Wo GEMM: grid (8, 32), direct store (no atomics) --------
__global__ __launch_bounds__(256) void gemm_wo(const __bf16* __restrict__ Ain,
                                               const __bf16* __restrict__ Bw,
                                               const float* __restrict__ bias,
                                               float* __restrict__ O) {
  GEMM_BK64_BODY(Ain, Bw, GK)

  const int row0 = bm + wm * 64;
  const int col0 = bn + wn * 64;
  for (int ni = 0; ni < 4; ni++) {
    const int col = col0 + ni * 16 + lr;
    const float bb = bias[col];
    for (int mi = 0; mi < 4; mi++) {
      const int row = row0 + mi * 16 + lq * 4;
      for (int r = 0; r < 4; r++)
        O[(size_t)(row + r) * GN + col] = acc[mi][ni][r] + bb;
    }
  }
}

// ---------------- fused flash attention v8 ----------------
// R6 structure (4 waves x 32 q-rows, LDS staging, S^T = K.Q^T, fast exp2,
// K=16 PV) + 256-key staging per barrier pair: Ks/Vs hold two 128-key halves
// (64 KB LDS), compute runs both halves between barriers. Halves the
// vmcnt(0)+s_barrier drain count (16 -> 8 per block).
__global__ __launch_bounds__(256, 2) void attn(const __bf16* __restrict__ Qh,
                                               const __bf16* __restrict__ Kh,
                                               const __bf16* __restrict__ Vt,
                                               __bf16* __restrict__ AO) {
  // per half: Ks [dchunk j 0..7][keyslot 0..127][8], keyslot = key ^ (2*(j&3))
  //           Vs [keychunk j2 0..15][dslot 0..63][8], dslot = d ^ (4*(j2&1))
  __shared__ __bf16 Ks[16384];
  __shared__ __bf16 Vs[16384];

  const int tid = threadIdx.x, w = tid >> 6, l = tid & 63;
  const int lr = l & 15, lq = l >> 4;
  const int bh = blockIdx.x;
  const int b = bh >> 4, h = bh & 15;
  const int q0 = blockIdx.y * 128 + w * 32;

  // Q as B-operand: B[n=q][k=d=kk*32+lq*8+j]  (Qh pre-scaled by QSCALE)
  bf16x8 qf[2][2];
  for (int mi = 0; mi < 2; mi++)
    for (int kk = 0; kk < 2; kk++)
      qf[mi][kk] = *(const bf16x8*)&Qh[((size_t)b * CS + q0 + mi * 16 + lr) * CE + h * CD + kk * 32 + lq * 8];

  f32x4 o[2][4] = {};
  float lsum[2] = {0.f, 0.f};
#if !PV_K16
  const bool hi_half = (lq & 1);
#endif

  for (int kt = 0; kt < CS / 256; kt++) {
    __syncthreads();
    // stage 256 keys = two 128-key halves (R6-verified per-half mapping)
    for (int i = 0; i < 8; i++) {
      const int half = i >> 2, ii = i & 3;
      const int j = w * 2 + (ii >> 1), hf = ii & 1;
      const int key = (hf * 64 + l) ^ ((j & 3) * 2);
      gload_lds16(&Kh[((size_t)b * CS + kt * 256 + half * 128 + key) * CE + h * CD + j * 8],
                  &Ks[half * 8192 + (j * 128 + hf * 64) * 8]);
    }
    for (int i = 0; i < 8; i++) {
      const int half = i >> 2, ii = i & 3;
      const int j2 = w * 4 + ii;
      const int d = l ^ ((j2 & 1) * 4);
      gload_lds16(&Vt[((size_t)bh * CD + d) * CS + kt * 256 + half * 128 + j2 * 8],
                  &Vs[half * 8192 + (j2 * 64) * 8]);
    }
    __syncthreads();

    for (int half = 0; half < 2; half++) {
      const __bf16* Ksb = &Ks[half * 8192];
      const __bf16* Vsb = &Vs[half * 8192];

      // S^T = K.Q^T : sa[mi][ni][r] <-> key = ni*16+lq*4+r, q = q0+mi*16+lr
      f32x4 sa[2][8] = {};
      for (int kk = 0; kk < 2; kk++) {
        bf16x8 kf[8];
        for (int ni = 0; ni < 8; ni++)
          kf[ni] = *(const bf16x8*)&Ksb[((kk * 4 + lq) * 128 + ((ni * 16 + lr) ^ (lq * 2))) * 8];
        for (int mi = 0; mi < 2; mi++)
          for (int ni = 0; ni < 8; ni++)
            sa[mi][ni] = __builtin_amdgcn_mfma_f32_16x16x32_bf16(kf[ni], qf[mi][kk], sa[mi][ni], 0, 0, 0);
      }

#if PV_K16
      // exp2 + direct K=16 A-frag; V b64 frags shared across both q-halves
      for (int ni = 0; ni < 8; ni++) {
        s16x4 pa4[2];
        for (int mi = 0; mi < 2; mi++)
          for (int r = 0; r < 4; r++) {
            const float p = EXP2(sa[mi][ni][r]);
            lsum[mi] += p;
            pa4[mi][r] = bf2s((__bf16)p);
          }
        const int j2 = ni * 2 + (lq >> 1);
        const int base = j2 * 64;
        const int sw = (j2 & 1) * 4;
        for (int di = 0; di < 4; di++) {
          const int dslot = (di * 16 + lr) ^ sw;
          const s16x4 vb4 = *(const s16x4*)&Vsb[(base + dslot) * 8 + (lq & 1) * 4];
          for (int mi = 0; mi < 2; mi++)
            o[mi][di] = MFMA16(pa4[mi], vb4, o[mi][di]);
        }
      }
#else
      // fallback: zero-padded K=32 PV
      for (int ni = 0; ni < 8; ni++) {
        bf16x8 pa[2];
        for (int mi = 0; mi < 2; mi++) {
          bf16x8 f;
          for (int r = 0; r < 4; r++) {
            const float p = EXP2(sa[mi][ni][r]);
            lsum[mi] += p;
            const __bf16 bv = (__bf16)p;
            f[r]     = hi_half ? (__bf16)0.f : bv;
            f[4 + r] = hi_half ? bv : (__bf16)0.f;
          }
          pa[mi] = f;
        }
        for (int di = 0; di < 4; di++) {
          const bf16x8 vb = *(const bf16x8*)&Vsb[((ni * 2 + (lq >> 1)) * 64 + ((di * 16 + lr) ^ ((lq >> 1) * 4))) * 8];
          for (int mi = 0; mi < 2; mi++)
            o[mi][di] = __builtin_amdgcn_mfma_f32_16x16x32_bf16(pa[mi], vb, o[mi][di], 0, 0, 0);
        }
      }
#endif
    }
  }

  // deferred row-sum: lane partial for q = q0+mi*16+lr over keys {16ni+lq*4+r}
  for (int mi = 0; mi < 2; mi++) {
    lsum[mi] += __shfl_xor(lsum[mi], 16, 64);
    lsum[mi] += __shfl_xor(lsum[mi], 32, 64);
  }

  // o C-layout: row q_local = lq*4+r, col d = di*16+lr
  for (int mi = 0; mi < 2; mi++) {
    f32x4 rv;
    for (int r = 0; r < 4; r++) rv[r] = 1.0f / __shfl(lsum[mi], lq * 4 + r, 64);
    for (int di = 0; di < 4; di++)
      for (int r = 0; r < 4; r++) {
        const size_t s = q0 + mi * 16 + lq * 4 + r;
        AO[((size_t)b * CS + s) * CE + h * CD + di * 16 + lr] = (__bf16)(o[mi][di][r] * rv[r]);
      }
  }
}

// ---------------- launch ----------------
extern "C" void kernel_launch(void* const* d_in, const int* in_sizes, int n_in,
                              void* d_out, int out_size, void* d_ws, size_t ws_size,
                              hipStream_t stream) {
  (void)in_sizes; (void)n_in; (void)out_size; (void)ws_size;
  const float* q  = (const float*)d_in[0];
  const float* k  = (const float*)d_in[1];
  const float* v  = (const float*)d_in[2];
  const float* Wq = (const float*)d_in[3];
  const float* bq = (const float*)d_in[4];
  const float* Wk = (const float*)d_in[5];
  const float* bk = (const float*)d_in[6];
  const float* Wv = (const float*)d_in[7];
  const float* bv = (const float*)d_in[8];
  const float* Wo = (const float*)d_in[9];
  const float* bo = (const float*)d_in[10];

  __bf16* ws = (__bf16*)d_ws;
  __bf16 *Wq_b = ws + WS_WQ, *Wk_b = ws + WS_WK, *Wv_b = ws + WS_WV, *Wo_b = ws + WS_WO;
  __bf16 *Xq = ws + WS_XQ, *Xk = ws + WS_XK, *Xv = ws + WS_XV;
  __bf16 *Qh = ws + WS_QH, *Kh = ws + WS_KH, *Vt = ws + WS_VT;
  __bf16 *AO = ws + WS_AO;

  convert_all<<<8192, 256, 0, stream>>>(q, k, v, Wq, Wk, Wv, Wo, ws);

  qkv_gemm<<<dim3(GN / 128, GM / 128, 3), 256, 0, stream>>>(
      Xq, Xk, Xv, Wq_b, Wk_b, Wv_b, bq, bk, bv, Qh, Kh, Vt);

  attn<<<dim3(CB * CH, CS / 128), 256, 0, stream>>>(Qh, Kh, Vt, AO);

  gemm_wo<<<dim3(GN / 128, GM / 128), 256, 0, stream>>>(AO, Wo_b, bo, (float*)d_out);
}

// Round 9
// 233.195 us; speedup vs baseline: 2.1981x; 1.4130x over previous
//
#include <hip/hip_runtime.h>

// ---------------- types ----------------
typedef __bf16 bf16x8 __attribute__((ext_vector_type(8)));
typedef __bf16 bf16x4 __attribute__((ext_vector_type(4)));
typedef float  f32x4  __attribute__((ext_vector_type(4)));
typedef short  s16x4  __attribute__((ext_vector_type(4)));

#define AS1 __attribute__((address_space(1)))
#define AS3 __attribute__((address_space(3)))

__device__ inline void gload_lds16(const void* g, void* l) {
  __builtin_amdgcn_global_load_lds((AS1 void*)(g), (AS3 void*)(l), 16, 0, 0);
}

#if __has_builtin(__builtin_amdgcn_exp2f)
#define EXP2(x) __builtin_amdgcn_exp2f(x)
#else
#define EXP2(x) exp2f(x)
#endif

#if __has_builtin(__builtin_amdgcn_mfma_f32_16x16x16bf16_1k)
#define PV_K16 1
#define MFMA16(a, b, c) __builtin_amdgcn_mfma_f32_16x16x16bf16_1k(a, b, c, 0, 0, 0)
#else
#define PV_K16 0
#endif

__device__ inline short bf2s(__bf16 x) {
  union { __bf16 b; short s; } u; u.b = x; return u.s;
}

// ---------------- constants ----------------
#define CB 2
#define CS 2048
#define CE 1024
#define CH 16
#define CD 64
#define GM 4096
#define GN 1024
#define GK 1024

// Q pre-scale: (1/sqrt(H)) * log2(e) so attn uses exp2 directly.
#define QSCALE 0.36067376022224087f

// workspace element offsets (__bf16 units)
#define WS_WQ  0
#define WS_WK  1048576
#define WS_WV  2097152
#define WS_WO  3145728
#define WS_XQ  4194304
#define WS_XK  8388608
#define WS_XV  12582912
#define WS_QH  16777216
#define WS_KH  20971520
#define WS_VT  25165824
#define WS_AO  WS_XQ   // Xq dead when attention writes AO

// ---------------- fp32 -> bf16 conversion (16 elems/thread) ----------------
__global__ __launch_bounds__(256) void convert_all(
    const float* __restrict__ q, const float* __restrict__ k, const float* __restrict__ v,
    const float* __restrict__ wq, const float* __restrict__ wk,
    const float* __restrict__ wv, const float* __restrict__ wo,
    __bf16* __restrict__ ws) {
  long idx = ((long)blockIdx.x * 256 + threadIdx.x) * 16;
  const float* src;
  __bf16* dst;
  if (idx < 12582912) {
    int a = (int)(idx >> 22);
    long within = idx & 4194303;
    src = (a == 0 ? q : (a == 1 ? k : v)) + within;
    dst = ws + WS_XQ + (long)a * 4194304 + within;
  } else {
    long widx = idx - 12582912;
    int a = (int)(widx >> 20);
    long within = widx & 1048575;
    src = (a == 0 ? wq : (a == 1 ? wk : (a == 2 ? wv : wo))) + within;
    dst = ws + widx;
  }
  for (int half = 0; half < 2; half++) {
    float4 f0 = *(const float4*)(src + half * 8);
    float4 f1 = *(const float4*)(src + half * 8 + 4);
    bf16x8 o;
    o[0] = (__bf16)f0.x; o[1] = (__bf16)f0.y; o[2] = (__bf16)f0.z; o[3] = (__bf16)f0.w;
    o[4] = (__bf16)f1.x; o[5] = (__bf16)f1.y; o[6] = (__bf16)f1.z; o[7] = (__bf16)f1.w;
    *(bf16x8*)(dst + half * 8) = o;
  }
}

// ======== BK=64 GEMM core with XOR-swizzled LDS (R4, conflict-free) ========
#define GEMM_BK64_BODY(A_PTR, B_PTR, KLEN)                                          \
  __shared__ __bf16 As[8192];                                                       \
  __shared__ __bf16 Bs[8192];                                                       \
  const int tid = threadIdx.x;                                                      \
  const int w = tid >> 6, l = tid & 63;                                             \
  const int wm = w >> 1, wn = w & 1;                                                \
  const int bm = blockIdx.y * 128, bn = blockIdx.x * 128;                           \
  const int lr = l & 15, lq = l >> 4;                                               \
  f32x4 acc[4][4] = {};                                                             \
  const int srow = w * 8 + (l >> 3);                                                \
  const int scol = ((l & 7) ^ ((l >> 3) & 7)) * 8;                                  \
  const __bf16* ga0 = (A_PTR) + (size_t)(bm + srow) * GK + scol;                    \
  const __bf16* gb0 = (B_PTR) + (size_t)(bn + srow) * GK + scol;                    \
  const int dstg = w * 64 + l;                                                      \
  for (int k0 = 0; k0 < (KLEN); k0 += 64) {                                         \
    __syncthreads();                                                                \
    for (int i = 0; i < 4; i++) {                                                   \
      gload_lds16(ga0 + (size_t)(i * 32) * GK + k0, &As[(i * 256 + dstg) * 8]);     \
      gload_lds16(gb0 + (size_t)(i * 32) * GK + k0, &Bs[(i * 256 + dstg) * 8]);     \
    }                                                                               \
    __syncthreads();                                                                \
    for (int kk = 0; kk < 2; kk++) {                                                \
      bf16x8 af[4], bfr[4];                                                         \
      for (int mi = 0; mi < 4; mi++) {                                              \
        const int row = wm * 64 + mi * 16 + lr;                                     \
        af[mi] = *(const bf16x8*)&As[(row * 8 + ((kk * 4 + lq) ^ (row & 7))) * 8];  \
      }                                                                             \
      for (int ni = 0; ni < 4; ni++) {                                              \
        const int row = wn * 64 + ni * 16 + lr;                                     \
        bfr[ni] = *(const bf16x8*)&Bs[(row * 8 + ((kk * 4 + lq) ^ (row & 7))) * 8]; \
      }                                                                             \
      for (int mi = 0; mi < 4; mi++)                                                \
        for (int ni = 0; ni < 4; ni++)                                              \
          acc[mi][ni] = __builtin_amdgcn_mfma_f32_16x16x32_bf16(af[mi], bfr[ni],    \
                                                                acc[mi][ni], 0, 0, 0); \
    }                                                                               \
  }

// ---------------- fused QKV GEMM: grid (8, 32, 3) ----------------
__global__ __launch_bounds__(256) void qkv_gemm(
    const __bf16* __restrict__ Xq, const __bf16* __restrict__ Xk, const __bf16* __restrict__ Xv,
    const __bf16* __restrict__ Wq, const __bf16* __restrict__ Wk, const __bf16* __restrict__ Wv,
    const float* __restrict__ bq, const float* __restrict__ bk, const float* __restrict__ bv,
    __bf16* __restrict__ Qh, __bf16* __restrict__ Kh, __bf16* __restrict__ Vt) {
  const int mode = blockIdx.z;
  const __bf16* A  = mode == 0 ? Xq : (mode == 1 ? Xk : Xv);
  const __bf16* Bw = mode == 0 ? Wq : (mode == 1 ? Wk : Wv);
  const float* bias = mode == 0 ? bq : (mode == 1 ? bk : bv);

  GEMM_BK64_BODY(A, Bw, GK)

  const int row0 = bm + wm * 64;
  const int col0 = bn + wn * 64;
  for (int ni = 0; ni < 4; ni++) {
    const int col = col0 + ni * 16 + lr;
    const float bb = bias[col];
    for (int mi = 0; mi < 4; mi++) {
      const int row = row0 + mi * 16 + lq * 4;
      if (mode == 0) {
        for (int r = 0; r < 4; r++)
          Qh[(size_t)(row + r) * GN + col] = (__bf16)((acc[mi][ni][r] + bb) * QSCALE);
      } else if (mode == 1) {
        for (int r = 0; r < 4; r++)
          Kh[(size_t)(row + r) * GN + col] = (__bf16)(acc[mi][ni][r] + bb);
      } else {
        const int b = row >> 11, s = row & 2047;
        const int h = col >> 6, d = col & 63;
        bf16x4 pk;
        for (int r = 0; r < 4; r++) pk[r] = (__bf16)(acc[mi][ni][r] + bb);
        *(bf16x4*)&Vt[(size_t)((b * CH + h) * CD + d) * CS + s] = pk;
      }
    }
  }
}

// ---------------- Wo GEMM: grid (8, 32), direct store (no atomics) --------
__global__ __launch_bounds__(256) void gemm_wo(const __bf16* __restrict__ Ain,
                                               const __bf16* __restrict__ Bw,
                                               const float* __restrict__ bias,
                                               float* __restrict__ O) {
  GEMM_BK64_BODY(Ain, Bw, GK)

  const int row0 = bm + wm * 64;
  const int col0 = bn + wn * 64;
  for (int ni = 0; ni < 4; ni++) {
    const int col = col0 + ni * 16 + lr;
    const float bb = bias[col];
    for (int mi = 0; mi < 4; mi++) {
      const int row = row0 + mi * 16 + lq * 4;
      for (int r = 0; r < 4; r++)
        O[(size_t)(row + r) * GN + col] = acc[mi][ni][r] + bb;
    }
  }
}

// ---------------- fused flash attention v9 ----------------
// R6 compute body (4 waves x 32 q-rows, 128-key tile, S^T = K.Q^T, fast exp2,
// K=16 PV) with REGISTER double-buffered staging: tile kt+1 is loaded into
// VGPRs (coalesced, same per-lane addresses the R6 DMA used) while tile kt
// computes; the barrier then only drains ds_writes, not global latency.
__global__ __launch_bounds__(256, 2) void attn(const __bf16* __restrict__ Qh,
                                               const __bf16* __restrict__ Kh,
                                               const __bf16* __restrict__ Vt,
                                               __bf16* __restrict__ AO) {
  // Ks: [dchunk j 0..7][keyslot 0..127][8], keyslot = key ^ (2*(j&3))
  // Vs: [keychunk j2 0..15][dslot 0..63][8], dslot = d ^ (4*(j2&1))
  __shared__ __bf16 Ks[8192];
  __shared__ __bf16 Vs[8192];

  const int tid = threadIdx.x, w = tid >> 6, l = tid & 63;
  const int lr = l & 15, lq = l >> 4;
  const int bh = blockIdx.x;
  const int b = bh >> 4, h = bh & 15;
  const int q0 = blockIdx.y * 128 + w * 32;

  // Q as B-operand: B[n=q][k=d=kk*32+lq*8+j]  (Qh pre-scaled by QSCALE)
  bf16x8 qf[2][2];
  for (int mi = 0; mi < 2; mi++)
    for (int kk = 0; kk < 2; kk++)
      qf[mi][kk] = *(const bf16x8*)&Qh[((size_t)b * CS + q0 + mi * 16 + lr) * CE + h * CD + kk * 32 + lq * 8];

  // per-lane staging source pointers (R6-verified mapping), advanced by kt
  const __bf16* ksrc[4];
  const __bf16* vsrc[4];
  int kdst[4], vdst[4];
  for (int i = 0; i < 4; i++) {
    const int j = w * 2 + (i >> 1), hf = i & 1;
    const int key = (hf * 64 + l) ^ ((j & 3) * 2);
    ksrc[i] = &Kh[((size_t)b * CS + key) * CE + h * CD + j * 8];
    kdst[i] = (j * 128 + hf * 64) * 8 + l * 8;
    const int j2 = w * 4 + i;
    const int d = l ^ ((j2 & 1) * 4);
    vsrc[i] = &Vt[((size_t)bh * CD + d) * CS + j2 * 8];
    vdst[i] = (j2 * 64) * 8 + l * 8;
  }

  f32x4 o[2][4] = {};
  float lsum[2] = {0.f, 0.f};
#if !PV_K16
  const bool hi_half = (lq & 1);
#endif

  // preload tile 0 into registers
  bf16x8 kreg[4], vreg[4];
  for (int i = 0; i < 4; i++) {
    kreg[i] = *(const bf16x8*)(ksrc[i]);
    vreg[i] = *(const bf16x8*)(vsrc[i]);
  }

  for (int kt = 0; kt < CS / 128; kt++) {
    __syncthreads();  // previous tile's readers done
    for (int i = 0; i < 4; i++) {
      *(bf16x8*)&Ks[kdst[i]] = kreg[i];
      *(bf16x8*)&Vs[vdst[i]] = vreg[i];
    }
    __syncthreads();  // drains only LDS writes (lgkm), not global latency

    // issue next tile's global loads; they complete during compute below
    if (kt + 1 < CS / 128) {
      for (int i = 0; i < 4; i++) {
        kreg[i] = *(const bf16x8*)(ksrc[i] + (size_t)(kt + 1) * 128 * CE);
        vreg[i] = *(const bf16x8*)(vsrc[i] + (size_t)(kt + 1) * 128);
      }
    }

    // S^T = K.Q^T : sa[mi][ni][r] <-> key = ni*16+lq*4+r, q = q0+mi*16+lr
    f32x4 sa[2][8] = {};
    for (int kk = 0; kk < 2; kk++) {
      bf16x8 kf[8];
      for (int ni = 0; ni < 8; ni++)
        kf[ni] = *(const bf16x8*)&Ks[((kk * 4 + lq) * 128 + ((ni * 16 + lr) ^ (lq * 2))) * 8];
      for (int mi = 0; mi < 2; mi++)
        for (int ni = 0; ni < 8; ni++)
          sa[mi][ni] = __builtin_amdgcn_mfma_f32_16x16x32_bf16(kf[ni], qf[mi][kk], sa[mi][ni], 0, 0, 0);
    }

#if PV_K16
    // exp2 + direct K=16 A-frag; V b64 frags shared across both q-halves
    for (int ni = 0; ni < 8; ni++) {
      s16x4 pa4[2];
      for (int mi = 0; mi < 2; mi++)
        for (int r = 0; r < 4; r++) {
          const float p = EXP2(sa[mi][ni][r]);
          lsum[mi] += p;
          pa4[mi][r] = bf2s((__bf16)p);
        }
      const int j2 = ni * 2 + (lq >> 1);
      const int base = j2 * 64;
      const int sw = (j2 & 1) * 4;
      for (int di = 0; di < 4; di++) {
        const int dslot = (di * 16 + lr) ^ sw;
        const s16x4 vb4 = *(const s16x4*)&Vs[(base + dslot) * 8 + (lq & 1) * 4];
        for (int mi = 0; mi < 2; mi++)
          o[mi][di] = MFMA16(pa4[mi], vb4, o[mi][di]);
      }
    }
#else
    // fallback: zero-padded K=32 PV
    for (int ni = 0; ni < 8; ni++) {
      bf16x8 pa[2];
      for (int mi = 0; mi < 2; mi++) {
        bf16x8 f;
        for (int r = 0; r < 4; r++) {
          const float p = EXP2(sa[mi][ni][r]);
          lsum[mi] += p;
          const __bf16 bv = (__bf16)p;
          f[r]     = hi_half ? (__bf16)0.f : bv;
          f[4 + r] = hi_half ? bv : (__bf16)0.f;
        }
        pa[mi] = f;
      }
      for (int di = 0; di < 4; di++) {
        const bf16x8 vb = *(const bf16x8*)&Vs[((ni * 2 + (lq >> 1)) * 64 + ((di * 16 + lr) ^ ((lq >> 1) * 4))) * 8];
        for (int mi = 0; mi < 2; mi++)
          o[mi][di] = __builtin_amdgcn_mfma_f32_16x16x32_bf16(pa[mi], vb, o[mi][di], 0, 0, 0);
      }
    }
#endif
  }

  // deferred row-sum: lane partial for q = q0+mi*16+lr over keys {16ni+lq*4+r}
  for (int mi = 0; mi < 2; mi++) {
    lsum[mi] += __shfl_xor(lsum[mi], 16, 64);
    lsum[mi] += __shfl_xor(lsum[mi], 32, 64);
  }

  // o C-layout: row q_local = lq*4+r, col d = di*16+lr
  for (int mi = 0; mi < 2; mi++) {
    f32x4 rv;
    for (int r = 0; r < 4; r++) rv[r] = 1.0f / __shfl(lsum[mi], lq * 4 + r, 64);
    for (int di = 0; di < 4; di++)
      for (int r = 0; r < 4; r++) {
        const size_t s = q0 + mi * 16 + lq * 4 + r;
        AO[((size_t)b * CS + s) * CE + h * CD + di * 16 + lr] = (__bf16)(o[mi][di][r] * rv[r]);
      }
  }
}

// ---------------- launch ----------------
extern "C" void kernel_launch(void* const* d_in, const int* in_sizes, int n_in,
                              void* d_out, int out_size, void* d_ws, size_t ws_size,
                              hipStream_t stream) {
  (void)in_sizes; (void)n_in; (void)out_size; (void)ws_size;
  const float* q  = (const float*)d_in[0];
  const float* k  = (const float*)d_in[1];
  const float* v  = (const float*)d_in[2];
  const float* Wq = (const float*)d_in[3];
  const float* bq = (const float*)d_in[4];
  const float* Wk = (const float*)d_in[5];
  const float* bk = (const float*)d_in[6];
  const float* Wv = (const float*)d_in[7];
  const float* bv = (const float*)d_in[8];
  const float* Wo = (const float*)d_in[9];
  const float* bo = (const float*)d_in[10];

  __bf16* ws = (__bf16*)d_ws;
  __bf16 *Wq_b = ws + WS_WQ, *Wk_b = ws + WS_WK, *Wv_b = ws + WS_WV, *Wo_b = ws + WS_WO;
  __bf16 *Xq = ws + WS_XQ, *Xk = ws + WS_XK, *Xv = ws + WS_XV;
  __bf16 *Qh = ws + WS_QH, *Kh = ws + WS_KH, *Vt = ws + WS_VT;
  __bf16 *AO = ws + WS_AO;

  convert_all<<<4096, 256, 0, stream>>>(q, k, v, Wq, Wk, Wv, Wo, ws);

  qkv_gemm<<<dim3(GN / 128, GM / 128, 3), 256, 0, stream>>>(
      Xq, Xk, Xv, Wq_b, Wk_b, Wv_b, bq, bk, bv, Qh, Kh, Vt);

  attn<<<dim3(CB * CH, CS / 128), 256, 0, stream>>>(Qh, Kh, Vt, AO);

  gemm_wo<<<dim3(GN / 128, GM / 128), 256, 0, stream>>>(AO, Wo_b, bo, (float*)d_out);
}